// Round 5
// baseline (947.177 us; speedup 1.0000x reference)
//
#include <hip/hip_runtime.h>
#include <hip/hip_bf16.h>

#define NN 100000
#define EE 1600000
#define NB_SCAN 391   // (NN+255)/256

typedef __attribute__((ext_vector_type(8))) short bf16x8;
typedef __attribute__((ext_vector_type(4))) float f32x4;
typedef __attribute__((ext_vector_type(4))) unsigned int u32x4;
typedef __attribute__((ext_vector_type(2))) unsigned int u32x2;

__device__ __forceinline__ unsigned int f2bf(float x) {
    union { float f; unsigned int u; } v; v.f = x;
    return (v.u + 0x7fffu + ((v.u >> 16) & 1u)) >> 16;
}
__device__ __forceinline__ unsigned int pack2(float a, float b) {
    return f2bf(a) | (f2bf(b) << 16);
}
__device__ __forceinline__ float bf2f(unsigned short s) {
    unsigned int u = ((unsigned int)s) << 16;
    return __builtin_bit_cast(float, u);
}

// ---------------- CSR build: zero -> count -> exclusive scan -> scatter ----------------

__global__ void k_zero(int* __restrict__ cnt) {
    int i = blockIdx.x * 256 + threadIdx.x;
    if (i < NN) cnt[i] = 0;
}

__global__ void k_count(const int* __restrict__ dst, int* __restrict__ cnt) {
    int e = blockIdx.x * 256 + threadIdx.x;
    if (e < EE) atomicAdd(&cnt[dst[e]], 1);
}

__global__ void k_scan1(const int* __restrict__ cnt, int* __restrict__ offs,
                        int* __restrict__ part) {
    __shared__ int s[256];
    const int t = threadIdx.x;
    const int i = blockIdx.x * 256 + t;
    int v = (i < NN) ? cnt[i] : 0;
    s[t] = v; __syncthreads();
    for (int d = 1; d < 256; d <<= 1) {
        int o = (t >= d) ? s[t - d] : 0;
        __syncthreads();
        s[t] += o;
        __syncthreads();
    }
    if (i < NN) offs[i] = s[t] - v;            // block-local exclusive
    if (t == 255) part[blockIdx.x] = s[255];   // block total
}

__global__ void k_scan2(int* __restrict__ part) {
    __shared__ int s[512];
    const int t = threadIdx.x;
    int v = (t < NB_SCAN) ? part[t] : 0;
    s[t] = v; __syncthreads();
    for (int d = 1; d < 512; d <<= 1) {
        int o = (t >= d) ? s[t - d] : 0;
        __syncthreads();
        s[t] += o;
        __syncthreads();
    }
    if (t < NB_SCAN) part[t] = s[t] - v;       // exclusive over partials
}

__global__ void k_scan3(const int* __restrict__ cnt, const int* __restrict__ offs,
                        const int* __restrict__ part, int* __restrict__ offg,
                        int* __restrict__ cur, float* __restrict__ inv) {
    int i = blockIdx.x * 256 + threadIdx.x;
    if (i < NN) {
        int g = offs[i] + part[blockIdx.x];
        offg[i] = g;
        cur[i]  = g;
        int c = cnt[i];
        inv[i] = (c > 0) ? (1.0f / (float)c) : 0.0f;
    }
}

__global__ void k_scatter(const int* __restrict__ dst, const int* __restrict__ src,
                          int* __restrict__ cur, int2* __restrict__ ep2) {
    int e = blockIdx.x * 256 + threadIdx.x;
    if (e < EE) {
        int p = atomicAdd(&cur[dst[e]], 1);
        ep2[p] = make_int2(e, src[e]);
    }
}

// ---------------- weight pack into B-fragment lane order ----------------
// pW[((nt*KC)+kc)*64 + lane] = 8 bf16 at k = kc*32 + (lane>>4)*8 + j, n = nt*16 + (lane&15)
__global__ void k_packW(const float* __restrict__ W, u32x4* __restrict__ pW,
                        int KC, int NT, int NOUT) {
    int g = blockIdx.x * 256 + threadIdx.x;
    if (g >= NT * KC * 64) return;
    int lane = g & 63;
    int rest = g >> 6;
    int kc = rest % KC;
    int nt = rest / KC;
    int k0 = kc * 32 + ((lane >> 4) << 3);
    int n  = nt * 16 + (lane & 15);
    u32x4 u;
    #pragma unroll
    for (int t = 0; t < 4; ++t)
        u[t] = pack2(W[(k0 + 2 * t) * NOUT + n], W[(k0 + 2 * t + 1) * NOUT + n]);
    pW[g] = u;
}

// ================ fused layer 1 ================
// Per block: 128 nodes.
//  stage A-tile (K=128): cols 0-63 = inv*segsum(nfeats[src]), 64-127 = inv*segsum(efeats)  [also -> eaggm]
//  GEMM1 (W1m) -> h1 = A@W1m + b1m*msk  (in regs)
//  rewrite tile (K=192): cols 0-63 = nfeats, 64-191 = h1(bf16)
//  GEMM2 (W1a) -> x1 = relu(A@W1a + b1a) -> global bf16
__global__ __launch_bounds__(256)
void k_l1(const float* __restrict__ efeats, const float* __restrict__ nfeats,
          const int2* __restrict__ ep2, const int* __restrict__ offg,
          const int* __restrict__ cnt, const float* __restrict__ inv,
          const float* __restrict__ b1m, const float* __restrict__ b1a,
          const u32x4* __restrict__ pW1m, const u32x4* __restrict__ pW1a,
          unsigned short* __restrict__ eaggm, unsigned short* __restrict__ x1)
{
    __shared__ __align__(16) u32x2 A2[128 * 48];   // 48 KB; K<=192
    u32x4* A4 = (u32x4*)A2;
    unsigned short* AS = (unsigned short*)A2;

    const int tid  = threadIdx.x;
    const int lane = tid & 63;
    const int w    = tid >> 6;
    const int tileM = blockIdx.x * 128;
    const int s_ = lane >> 4;   // edge slot 0..3
    const int c  = lane & 15;   // 16B chunk

    // ---- stage 1: gather-mean, 32 nodes per wave ----
    for (int i = 0; i < 32; ++i) {
        const int r = w * 32 + i;
        const int v = tileM + r;
        float ax[4], ae[4];
        #pragma unroll
        for (int q = 0; q < 4; ++q) { ax[q] = 0.f; ae[q] = 0.f; }
        if (v < NN) {
            const int start = offg[v];
            const int d = cnt[v];
            for (int it = 0; it < d; it += 4) {
                const int j = it + s_;
                if (j < d) {
                    const int2 p = ep2[start + j];
                    f32x4 ue = *(const f32x4*)(efeats + (size_t)p.x * 64 + c * 4);
                    f32x4 ux = *(const f32x4*)(nfeats + (size_t)p.y * 64 + c * 4);
                    #pragma unroll
                    for (int q = 0; q < 4; ++q) { ae[q] += ue[q]; ax[q] += ux[q]; }
                }
            }
            #pragma unroll
            for (int q = 0; q < 4; ++q) {
                ae[q] += __shfl_xor(ae[q], 16);
                ae[q] += __shfl_xor(ae[q], 32);
                ax[q] += __shfl_xor(ax[q], 16);
                ax[q] += __shfl_xor(ax[q], 32);
            }
        }
        if (s_ == 0) {
            const float iv = (v < NN) ? inv[v] : 0.f;
            u32x2 ox, oe;
            ox[0] = pack2(ax[0] * iv, ax[1] * iv);
            ox[1] = pack2(ax[2] * iv, ax[3] * iv);
            oe[0] = pack2(ae[0] * iv, ae[1] * iv);
            oe[1] = pack2(ae[2] * iv, ae[3] * iv);
            const int sw = r & 7;
            const int q16 = c >> 1, sub = c & 1;
            A2[r * 32 + (((q16 ^ sw) << 1) | sub)]       = ox;   // cols 0-63
            A2[r * 32 + ((((8 + q16) ^ sw) << 1) | sub)] = oe;   // cols 64-127
            if (v < NN) *(u32x2*)(eaggm + (size_t)v * 64 + c * 4) = oe;
        }
    }
    __syncthreads();

    // ---- GEMM1: K=128 (stride 16 units), NOUT=128, NT=4 ----
    const int rowBase = (w >> 1) * 64;
    const int ctBase  = (w & 1) * 4;
    const int lrow    = lane & 15;
    const int kq      = lane >> 4;

    f32x4 acc[4][4];
    #pragma unroll
    for (int mt = 0; mt < 4; ++mt)
        #pragma unroll
        for (int nt = 0; nt < 4; ++nt)
            #pragma unroll
            for (int q = 0; q < 4; ++q) acc[mt][nt][q] = 0.f;

    #pragma unroll
    for (int kc = 0; kc < 4; ++kc) {
        bf16x8 a[4];
        #pragma unroll
        for (int mt = 0; mt < 4; ++mt) {
            const int row = rowBase + mt * 16 + lrow;
            a[mt] = __builtin_bit_cast(bf16x8, A4[row * 16 + ((kc * 4 + kq) ^ (row & 7))]);
        }
        #pragma unroll
        for (int nt = 0; nt < 4; ++nt) {
            bf16x8 b = __builtin_bit_cast(bf16x8, pW1m[(size_t)((ctBase + nt) * 4 + kc) * 64 + lane]);
            #pragma unroll
            for (int mt = 0; mt < 4; ++mt)
                acc[mt][nt] = __builtin_amdgcn_mfma_f32_16x16x32_bf16(a[mt], b, acc[mt][nt], 0, 0, 0);
        }
    }
    __syncthreads();   // all waves done reading GEMM1 tile

    // ---- rewrite tile as K=192 (stride 24 units): cols 0-63 nfeats, 64-191 h1 ----
    for (int idx = tid; idx < 128 * 8; idx += 256) {
        const int row = idx >> 3;
        const int u   = idx & 7;
        const int gr  = tileM + row;
        u32x4 o; o[0]=o[1]=o[2]=o[3]=0u;
        if (gr < NN) {
            const f32x4* pv = (const f32x4*)(nfeats + (size_t)gr * 64 + u * 8);
            f32x4 f0 = pv[0], f1 = pv[1];
            o[0] = pack2(f0[0], f0[1]); o[1] = pack2(f0[2], f0[3]);
            o[2] = pack2(f1[0], f1[1]); o[3] = pack2(f1[2], f1[3]);
        }
        A4[row * 24 + (u ^ (row & 7))] = o;
    }
    {
        float bb[4];
        #pragma unroll
        for (int nt = 0; nt < 4; ++nt) bb[nt] = b1m[(ctBase + nt) * 16 + lrow];
        #pragma unroll
        for (int mt = 0; mt < 4; ++mt) {
            #pragma unroll
            for (int j = 0; j < 4; ++j) {
                const int r  = rowBase + mt * 16 + kq * 4 + j;
                const int gr = tileM + r;
                const float msk = (gr < NN && inv[gr] > 0.f) ? 1.f : 0.f;
                #pragma unroll
                for (int nt = 0; nt < 4; ++nt) {
                    const int col = 64 + (ctBase + nt) * 16 + lrow;
                    const float val = acc[mt][nt][j] + bb[nt] * msk;
                    AS[(r * 24 + ((col >> 3) ^ (r & 7))) * 8 + (col & 7)] = (unsigned short)f2bf(val);
                }
            }
        }
    }
    __syncthreads();

    // ---- GEMM2: K=192 (stride 24), NOUT=128, W1a -> relu -> x1 ----
    f32x4 acc2[4][4];
    #pragma unroll
    for (int mt = 0; mt < 4; ++mt)
        #pragma unroll
        for (int nt = 0; nt < 4; ++nt)
            #pragma unroll
            for (int q = 0; q < 4; ++q) acc2[mt][nt][q] = 0.f;

    #pragma unroll
    for (int kc = 0; kc < 6; ++kc) {
        bf16x8 a[4];
        #pragma unroll
        for (int mt = 0; mt < 4; ++mt) {
            const int row = rowBase + mt * 16 + lrow;
            a[mt] = __builtin_bit_cast(bf16x8, A4[row * 24 + ((kc * 4 + kq) ^ (row & 7))]);
        }
        #pragma unroll
        for (int nt = 0; nt < 4; ++nt) {
            bf16x8 b = __builtin_bit_cast(bf16x8, pW1a[(size_t)((ctBase + nt) * 6 + kc) * 64 + lane]);
            #pragma unroll
            for (int mt = 0; mt < 4; ++mt)
                acc2[mt][nt] = __builtin_amdgcn_mfma_f32_16x16x32_bf16(a[mt], b, acc2[mt][nt], 0, 0, 0);
        }
    }
    {
        float bb[4];
        #pragma unroll
        for (int nt = 0; nt < 4; ++nt) bb[nt] = b1a[(ctBase + nt) * 16 + lrow];
        #pragma unroll
        for (int mt = 0; mt < 4; ++mt) {
            #pragma unroll
            for (int j = 0; j < 4; ++j) {
                const int gr = tileM + rowBase + mt * 16 + kq * 4 + j;
                if (gr < NN) {
                    #pragma unroll
                    for (int nt = 0; nt < 4; ++nt) {
                        const float v = fmaxf(acc2[mt][nt][j] + bb[nt], 0.f);
                        x1[(size_t)gr * 128 + (ctBase + nt) * 16 + lrow] = (unsigned short)f2bf(v);
                    }
                }
            }
        }
    }
}

// ================ fused layer 2 ================
// Per block: 128 nodes.
//  stage A-tile (K=192): cols 0-127 = inv*segsum(x1[src]), 128-191 = eaggm
//  GEMM1 (W2m) -> h2 = A@W2m + b2m*msk (regs)
//  rewrite: cols 0-127 = x1, 128-191 = h2(bf16)
//  GEMM2 (W2a) -> out = relu(A@W2a + b2a) f32
__global__ __launch_bounds__(256)
void k_l2(const unsigned short* __restrict__ x1, const unsigned short* __restrict__ eaggm,
          const int2* __restrict__ ep2, const int* __restrict__ offg,
          const int* __restrict__ cnt, const float* __restrict__ inv,
          const float* __restrict__ b2m, const float* __restrict__ b2a,
          const u32x4* __restrict__ pW2m, const u32x4* __restrict__ pW2a,
          float* __restrict__ out)
{
    __shared__ __align__(16) u32x2 A2[128 * 48];
    u32x4* A4 = (u32x4*)A2;
    unsigned short* AS = (unsigned short*)A2;

    const int tid  = threadIdx.x;
    const int lane = tid & 63;
    const int w    = tid >> 6;
    const int tileM = blockIdx.x * 128;
    const int s_ = lane >> 4;
    const int c  = lane & 15;

    // ---- stage 1: gather-mean of x1[src] + eaggm load, 32 nodes per wave ----
    for (int i = 0; i < 32; ++i) {
        const int r = w * 32 + i;
        const int v = tileM + r;
        float am[8];
        #pragma unroll
        for (int q = 0; q < 8; ++q) am[q] = 0.f;
        if (v < NN) {
            const int start = offg[v];
            const int d = cnt[v];
            for (int it = 0; it < d; it += 4) {
                const int j = it + s_;
                if (j < d) {
                    const int2 p = ep2[start + j];
                    bf16x8 u = *(const bf16x8*)(x1 + (size_t)p.y * 128 + c * 8);
                    #pragma unroll
                    for (int q = 0; q < 8; ++q) am[q] += bf2f((unsigned short)u[q]);
                }
            }
            #pragma unroll
            for (int q = 0; q < 8; ++q) {
                am[q] += __shfl_xor(am[q], 16);
                am[q] += __shfl_xor(am[q], 32);
            }
        }
        const int sw = r & 7;
        if (s_ == 0) {
            const float iv = (v < NN) ? inv[v] : 0.f;
            u32x4 o;
            #pragma unroll
            for (int t = 0; t < 4; ++t) o[t] = pack2(am[2*t] * iv, am[2*t+1] * iv);
            A4[r * 24 + (c ^ sw)] = o;                       // cols 0-127
        } else if (s_ == 1 && c < 8) {
            u32x4 o; o[0]=o[1]=o[2]=o[3]=0u;
            if (v < NN) o = *(const u32x4*)(eaggm + (size_t)v * 64 + c * 8);
            A4[r * 24 + ((16 + c) ^ sw)] = o;                // cols 128-191
        }
    }
    __syncthreads();

    // ---- GEMM1: K=192, NOUT=64, NT=2, W2m ----
    const int rowBase = (w >> 1) * 64;
    const int ctBase  = (w & 1) * 2;
    const int lrow    = lane & 15;
    const int kq      = lane >> 4;

    f32x4 acc[4][2];
    #pragma unroll
    for (int mt = 0; mt < 4; ++mt)
        #pragma unroll
        for (int nt = 0; nt < 2; ++nt)
            #pragma unroll
            for (int q = 0; q < 4; ++q) acc[mt][nt][q] = 0.f;

    #pragma unroll
    for (int kc = 0; kc < 6; ++kc) {
        bf16x8 a[4];
        #pragma unroll
        for (int mt = 0; mt < 4; ++mt) {
            const int row = rowBase + mt * 16 + lrow;
            a[mt] = __builtin_bit_cast(bf16x8, A4[row * 24 + ((kc * 4 + kq) ^ (row & 7))]);
        }
        #pragma unroll
        for (int nt = 0; nt < 2; ++nt) {
            bf16x8 b = __builtin_bit_cast(bf16x8, pW2m[(size_t)((ctBase + nt) * 6 + kc) * 64 + lane]);
            #pragma unroll
            for (int mt = 0; mt < 4; ++mt)
                acc[mt][nt] = __builtin_amdgcn_mfma_f32_16x16x32_bf16(a[mt], b, acc[mt][nt], 0, 0, 0);
        }
    }
    __syncthreads();

    // ---- rewrite: cols 0-127 = x1 rows (coalesced), cols 128-191 = h2 ----
    for (int idx = tid; idx < 128 * 16; idx += 256) {
        const int row = idx >> 4;
        const int u   = idx & 15;
        const int gr  = tileM + row;
        u32x4 o; o[0]=o[1]=o[2]=o[3]=0u;
        if (gr < NN) o = *(const u32x4*)(x1 + (size_t)gr * 128 + u * 8);
        A4[row * 24 + (u ^ (row & 7))] = o;
    }
    {
        float bb[2];
        #pragma unroll
        for (int nt = 0; nt < 2; ++nt) bb[nt] = b2m[(ctBase + nt) * 16 + lrow];
        #pragma unroll
        for (int mt = 0; mt < 4; ++mt) {
            #pragma unroll
            for (int j = 0; j < 4; ++j) {
                const int r  = rowBase + mt * 16 + kq * 4 + j;
                const int gr = tileM + r;
                const float msk = (gr < NN && inv[gr] > 0.f) ? 1.f : 0.f;
                #pragma unroll
                for (int nt = 0; nt < 2; ++nt) {
                    const int col = 128 + (ctBase + nt) * 16 + lrow;
                    const float val = acc[mt][nt][j] + bb[nt] * msk;
                    AS[(r * 24 + ((col >> 3) ^ (r & 7))) * 8 + (col & 7)] = (unsigned short)f2bf(val);
                }
            }
        }
    }
    __syncthreads();

    // ---- GEMM2: K=192, NOUT=64, W2a -> relu -> out f32 ----
    f32x4 acc2[4][2];
    #pragma unroll
    for (int mt = 0; mt < 4; ++mt)
        #pragma unroll
        for (int nt = 0; nt < 2; ++nt)
            #pragma unroll
            for (int q = 0; q < 4; ++q) acc2[mt][nt][q] = 0.f;

    #pragma unroll
    for (int kc = 0; kc < 6; ++kc) {
        bf16x8 a[4];
        #pragma unroll
        for (int mt = 0; mt < 4; ++mt) {
            const int row = rowBase + mt * 16 + lrow;
            a[mt] = __builtin_bit_cast(bf16x8, A4[row * 24 + ((kc * 4 + kq) ^ (row & 7))]);
        }
        #pragma unroll
        for (int nt = 0; nt < 2; ++nt) {
            bf16x8 b = __builtin_bit_cast(bf16x8, pW2a[(size_t)((ctBase + nt) * 6 + kc) * 64 + lane]);
            #pragma unroll
            for (int mt = 0; mt < 4; ++mt)
                acc2[mt][nt] = __builtin_amdgcn_mfma_f32_16x16x32_bf16(a[mt], b, acc2[mt][nt], 0, 0, 0);
        }
    }
    {
        float bb[2];
        #pragma unroll
        for (int nt = 0; nt < 2; ++nt) bb[nt] = b2a[(ctBase + nt) * 16 + lrow];
        #pragma unroll
        for (int mt = 0; mt < 4; ++mt) {
            #pragma unroll
            for (int j = 0; j < 4; ++j) {
                const int gr = tileM + rowBase + mt * 16 + kq * 4 + j;
                if (gr < NN) {
                    #pragma unroll
                    for (int nt = 0; nt < 2; ++nt) {
                        const float v = fmaxf(acc2[mt][nt][j] + bb[nt], 0.f);
                        out[(size_t)gr * 64 + (ctBase + nt) * 16 + lrow] = v;
                    }
                }
            }
        }
    }
}

extern "C" void kernel_launch(void* const* d_in, const int* in_sizes, int n_in,
                              void* d_out, int out_size, void* d_ws, size_t ws_size,
                              hipStream_t stream) {
    const float* nfeats = (const float*)d_in[0];
    const float* efeats = (const float*)d_in[1];
    const int*   src    = (const int*)d_in[2];
    const int*   dst    = (const int*)d_in[3];
    const float* W1m = (const float*)d_in[4];
    const float* b1m = (const float*)d_in[5];
    const float* W1a = (const float*)d_in[6];
    const float* b1a = (const float*)d_in[7];
    const float* W2m = (const float*)d_in[8];
    const float* b2m = (const float*)d_in[9];
    const float* W2a = (const float*)d_in[10];
    const float* b2a = (const float*)d_in[11];
    float* out = (float*)d_out;

    char* ws = (char*)d_ws;
    unsigned short* eaggm = (unsigned short*)(ws + 0);          // N*64 bf16  = 12.8 MB
    unsigned short* x1    = (unsigned short*)(ws + 12800000);   // N*128 bf16 = 25.6 MB
    int2*           ep2   = (int2*)(ws + 38400000);             // E int2 = 12.8 MB
    int*            cnt   = (int*)(ws + 51200000);              // N int
    int*            offs  = (int*)(ws + 51600000);              // N int
    int*            offg  = (int*)(ws + 52000000);              // N int
    int*            cur   = (int*)(ws + 52400000);              // N int
    int*            part  = (int*)(ws + 52800000);              // 512 int
    float*          inv   = (float*)(ws + 52802048);            // N f32
    u32x4* pW1m = (u32x4*)(ws + 53202048);                      // 32 KB
    u32x4* pW1a = (u32x4*)(ws + 53234816);                      // 48 KB
    u32x4* pW2m = (u32x4*)(ws + 53283968);                      // 24 KB
    u32x4* pW2a = (u32x4*)(ws + 53308544);                      // 24 KB

    // zero cnt with a kernel — in-graph fillBufferAligned measured pathological in R3
    k_zero<<<NB_SCAN, 256, 0, stream>>>(cnt);

    k_packW<<<(2048 + 255) / 256, 256, 0, stream>>>(W1m, pW1m, 4, 8, 128);
    k_packW<<<(3072 + 255) / 256, 256, 0, stream>>>(W1a, pW1a, 6, 8, 128);
    k_packW<<<(1536 + 255) / 256, 256, 0, stream>>>(W2m, pW2m, 6, 4, 64);
    k_packW<<<(1536 + 255) / 256, 256, 0, stream>>>(W2a, pW2a, 6, 4, 64);

    // CSR bucketing by dst
    k_count  <<<(EE + 255) / 256, 256, 0, stream>>>(dst, cnt);
    k_scan1  <<<NB_SCAN, 256, 0, stream>>>(cnt, offs, part);
    k_scan2  <<<1, 512, 0, stream>>>(part);
    k_scan3  <<<NB_SCAN, 256, 0, stream>>>(cnt, offs, part, offg, cur, inv);
    k_scatter<<<(EE + 255) / 256, 256, 0, stream>>>(dst, src, cur, ep2);

    const int NBG = (NN + 127) / 128;  // 782

    // fused layer 1: gather-mean -> W1m GEMM -> [nfeats|h1] -> W1a GEMM -> x1 (+ eaggm)
    k_l1<<<NBG, 256, 0, stream>>>(efeats, nfeats, ep2, offg, cnt, inv,
                                  b1m, b1a, pW1m, pW1a, eaggm, x1);
    // fused layer 2: gather-mean(x1) + eaggm -> W2m GEMM -> [x1|h2] -> W2a GEMM -> out
    k_l2<<<NBG, 256, 0, stream>>>(x1, eaggm, ep2, offg, cnt, inv,
                                  b2m, b2a, pW2m, pW2a, out);
}

// Round 6
// 467.907 us; speedup vs baseline: 2.0243x; 2.0243x over previous
//
#include <hip/hip_runtime.h>
#include <hip/hip_bf16.h>

#define NN 100000
#define EE 1600000
#define NB_SCAN 391   // (NN+255)/256

typedef __attribute__((ext_vector_type(8))) short bf16x8;
typedef __attribute__((ext_vector_type(4))) float f32x4;
typedef __attribute__((ext_vector_type(4))) unsigned int u32x4;
typedef __attribute__((ext_vector_type(2))) unsigned int u32x2;

__device__ __forceinline__ unsigned int f2bf(float x) {
    union { float f; unsigned int u; } v; v.f = x;
    return (v.u + 0x7fffu + ((v.u >> 16) & 1u)) >> 16;
}
__device__ __forceinline__ unsigned int pack2(float a, float b) {
    return f2bf(a) | (f2bf(b) << 16);
}
__device__ __forceinline__ float bf2f(unsigned short s) {
    unsigned int u = ((unsigned int)s) << 16;
    return __builtin_bit_cast(float, u);
}

// ---------------- init: zero cnt + pack all 4 weights (one launch) ----------------

__device__ __forceinline__ void packW_body(const float* __restrict__ W,
                                           u32x4* __restrict__ pW,
                                           int KC, int NT, int NOUT, int g) {
    if (g >= NT * KC * 64) return;
    int lane = g & 63;
    int rest = g >> 6;
    int kc = rest % KC;
    int nt = rest / KC;
    int k0 = kc * 32 + ((lane >> 4) << 3);
    int n  = nt * 16 + (lane & 15);
    u32x4 u;
    #pragma unroll
    for (int t = 0; t < 4; ++t)
        u[t] = pack2(W[(k0 + 2 * t) * NOUT + n], W[(k0 + 2 * t + 1) * NOUT + n]);
    pW[g] = u;
}

// blocks 0..390: zero cnt; 391..398: pW1m; 399..410: pW1a; 411..416: pW2m; 417..422: pW2a
__global__ void k_init(int* __restrict__ cnt,
                       const float* __restrict__ W1m, u32x4* __restrict__ pW1m,
                       const float* __restrict__ W1a, u32x4* __restrict__ pW1a,
                       const float* __restrict__ W2m, u32x4* __restrict__ pW2m,
                       const float* __restrict__ W2a, u32x4* __restrict__ pW2a) {
    const int b = blockIdx.x;
    const int t = threadIdx.x;
    if (b < 391) {
        int i = b * 256 + t;
        if (i < NN) cnt[i] = 0;
    } else if (b < 399) {
        packW_body(W1m, pW1m, 4, 8, 128, (b - 391) * 256 + t);
    } else if (b < 411) {
        packW_body(W1a, pW1a, 6, 8, 128, (b - 399) * 256 + t);
    } else if (b < 417) {
        packW_body(W2m, pW2m, 6, 4, 64, (b - 411) * 256 + t);
    } else {
        packW_body(W2a, pW2a, 6, 4, 64, (b - 417) * 256 + t);
    }
}

// ---------------- CSR build: count -> exclusive scan -> scatter ----------------

__global__ void k_count(const int* __restrict__ dst, int* __restrict__ cnt) {
    int e = blockIdx.x * 256 + threadIdx.x;
    if (e < EE) atomicAdd(&cnt[dst[e]], 1);
}

__global__ void k_scan1(const int* __restrict__ cnt, int* __restrict__ offs,
                        int* __restrict__ part) {
    __shared__ int s[256];
    const int t = threadIdx.x;
    const int i = blockIdx.x * 256 + t;
    int v = (i < NN) ? cnt[i] : 0;
    s[t] = v; __syncthreads();
    for (int d = 1; d < 256; d <<= 1) {
        int o = (t >= d) ? s[t - d] : 0;
        __syncthreads();
        s[t] += o;
        __syncthreads();
    }
    if (i < NN) offs[i] = s[t] - v;            // block-local exclusive
    if (t == 255) part[blockIdx.x] = s[255];   // block total
}

__global__ void k_scan2(int* __restrict__ part) {
    __shared__ int s[512];
    const int t = threadIdx.x;
    int v = (t < NB_SCAN) ? part[t] : 0;
    s[t] = v; __syncthreads();
    for (int d = 1; d < 512; d <<= 1) {
        int o = (t >= d) ? s[t - d] : 0;
        __syncthreads();
        s[t] += o;
        __syncthreads();
    }
    if (t < NB_SCAN) part[t] = s[t] - v;       // exclusive over partials
}

__global__ void k_scan3(const int* __restrict__ cnt, const int* __restrict__ offs,
                        const int* __restrict__ part, int* __restrict__ offg,
                        int* __restrict__ cur, float* __restrict__ inv) {
    int i = blockIdx.x * 256 + threadIdx.x;
    if (i < NN) {
        int g = offs[i] + part[blockIdx.x];
        offg[i] = g;
        cur[i]  = g;
        int c = cnt[i];
        inv[i] = (c > 0) ? (1.0f / (float)c) : 0.0f;
    }
}

__global__ void k_scatter(const int* __restrict__ dst, const int* __restrict__ src,
                          int* __restrict__ cur, int2* __restrict__ ep2) {
    int e = blockIdx.x * 256 + threadIdx.x;
    if (e < EE) {
        int p = atomicAdd(&cur[dst[e]], 1);
        ep2[p] = make_int2(e, src[e]);
    }
}

// ---------------- layer-1 gather-mean: 1 wave per node, 8 edges in flight ----------------
// eaggm[v]  = inv[v] * sum efeats[edge]   (HBM stream, 410 MB random 256B rows)
// xaggm1[v] = inv[v] * sum nfeats[src]    (cache-served gather)
__global__ __launch_bounds__(256)
void k_agg01(const float* __restrict__ efeats, const float* __restrict__ nfeats,
             const int2* __restrict__ ep2, const int* __restrict__ offg,
             const int* __restrict__ cnt, const float* __restrict__ inv,
             unsigned short* __restrict__ eaggm, unsigned short* __restrict__ xaggm1)
{
    const int v = blockIdx.x * 4 + (threadIdx.x >> 6);
    if (v >= NN) return;
    const int lane = threadIdx.x & 63;
    const int s_ = lane >> 4;   // edge slot 0..3
    const int c  = lane & 15;   // 16B chunk
    const int start = offg[v];
    const int d = cnt[v];
    const int2* bp = ep2 + start;

    float ae[4], ax[4];
    #pragma unroll
    for (int q = 0; q < 4; ++q) { ae[q] = 0.f; ax[q] = 0.f; }

    // 8 edges per iteration (2 per slot) -> 4 independent gathers in flight per lane
    for (int it = s_; it < d; it += 8) {
        const int j1 = it + 4;
        const int2 p0 = bp[it];
        const bool has1 = (j1 < d);
        const int2 p1 = has1 ? bp[j1] : p0;
        f32x4 ue0 = *(const f32x4*)(efeats + (size_t)p0.x * 64 + c * 4);
        f32x4 ux0 = *(const f32x4*)(nfeats + (size_t)p0.y * 64 + c * 4);
        f32x4 ue1 = *(const f32x4*)(efeats + (size_t)p1.x * 64 + c * 4);
        f32x4 ux1 = *(const f32x4*)(nfeats + (size_t)p1.y * 64 + c * 4);
        #pragma unroll
        for (int q = 0; q < 4; ++q) { ae[q] += ue0[q]; ax[q] += ux0[q]; }
        if (has1) {
            #pragma unroll
            for (int q = 0; q < 4; ++q) { ae[q] += ue1[q]; ax[q] += ux1[q]; }
        }
    }
    #pragma unroll
    for (int q = 0; q < 4; ++q) {
        ae[q] += __shfl_xor(ae[q], 16);
        ae[q] += __shfl_xor(ae[q], 32);
        ax[q] += __shfl_xor(ax[q], 16);
        ax[q] += __shfl_xor(ax[q], 32);
    }
    if (s_ == 0) {
        const float iv = inv[v];
        u32x2 oe, ox;
        oe[0] = pack2(ae[0] * iv, ae[1] * iv);
        oe[1] = pack2(ae[2] * iv, ae[3] * iv);
        ox[0] = pack2(ax[0] * iv, ax[1] * iv);
        ox[1] = pack2(ax[2] * iv, ax[3] * iv);
        *(u32x2*)(eaggm  + (size_t)v * 64 + c * 4) = oe;
        *(u32x2*)(xaggm1 + (size_t)v * 64 + c * 4) = ox;
    }
}

// ---------------- layer-2 gather-mean: xaggm2 = inv * segsum(x1[src]) ----------------
__global__ __launch_bounds__(256)
void k_agg2(const unsigned short* __restrict__ x1, const int2* __restrict__ ep2,
            const int* __restrict__ offg, const int* __restrict__ cnt,
            const float* __restrict__ inv, unsigned short* __restrict__ xaggm2)
{
    const int v = blockIdx.x * 4 + (threadIdx.x >> 6);
    if (v >= NN) return;
    const int lane = threadIdx.x & 63;
    const int s_ = lane >> 4;
    const int c  = lane & 15;
    const int start = offg[v];
    const int d = cnt[v];
    const int2* bp = ep2 + start;

    float acc[8];
    #pragma unroll
    for (int q = 0; q < 8; ++q) acc[q] = 0.f;

    for (int it = s_; it < d; it += 8) {
        const int j1 = it + 4;
        const int2 p0 = bp[it];
        const bool has1 = (j1 < d);
        const int2 p1 = has1 ? bp[j1] : p0;
        bf16x8 u0 = *(const bf16x8*)(x1 + (size_t)p0.y * 128 + c * 8);
        bf16x8 u1 = *(const bf16x8*)(x1 + (size_t)p1.y * 128 + c * 8);
        #pragma unroll
        for (int q = 0; q < 8; ++q) acc[q] += bf2f((unsigned short)u0[q]);
        if (has1) {
            #pragma unroll
            for (int q = 0; q < 8; ++q) acc[q] += bf2f((unsigned short)u1[q]);
        }
    }
    #pragma unroll
    for (int q = 0; q < 8; ++q) {
        acc[q] += __shfl_xor(acc[q], 16);
        acc[q] += __shfl_xor(acc[q], 32);
    }
    if (s_ == 0) {
        const float iv = inv[v];
        u32x4 o;
        #pragma unroll
        for (int t = 0; t < 4; ++t) o[t] = pack2(acc[2*t] * iv, acc[2*t+1] * iv);
        *(u32x4*)(xaggm2 + (size_t)v * 128 + c * 8) = o;
    }
}

// ================ fused layer-1 GEMM pair ================
// stage [xaggm1|eaggm] (K=128, coalesced bf16) -> GEMM W1m -> h1 regs
// restage [nfeats|h1] (K=192) -> GEMM W1a -> x1 = relu(...) bf16
__global__ __launch_bounds__(256)
void k_gl1(const float* __restrict__ nfeats,
           const unsigned short* __restrict__ xaggm1, const unsigned short* __restrict__ eaggm,
           const float* __restrict__ inv,
           const float* __restrict__ b1m, const float* __restrict__ b1a,
           const u32x4* __restrict__ pW1m, const u32x4* __restrict__ pW1a,
           unsigned short* __restrict__ x1)
{
    __shared__ __align__(16) u32x4 A4[128 * 24];   // 48 KB (K=192 layout; K=128 uses first 32 KB)
    unsigned short* AS = (unsigned short*)A4;

    const int tid  = threadIdx.x;
    const int lane = tid & 63;
    const int w    = tid >> 6;
    const int tileM = blockIdx.x * 128;

    // ---- stage [xaggm1|eaggm], K=128, stride 16 units ----
    for (int idx = tid; idx < 128 * 16; idx += 256) {
        const int row = idx >> 4;
        const int u   = idx & 15;
        const int gr  = tileM + row;
        u32x4 o; o[0]=o[1]=o[2]=o[3]=0u;
        if (gr < NN) {
            o = (u < 8) ? *(const u32x4*)(xaggm1 + (size_t)gr * 64 + u * 8)
                        : *(const u32x4*)(eaggm  + (size_t)gr * 64 + (u - 8) * 8);
        }
        A4[row * 16 + (u ^ (row & 7))] = o;
    }
    __syncthreads();

    const int rowBase = (w >> 1) * 64;
    const int ctBase  = (w & 1) * 4;
    const int lrow    = lane & 15;
    const int kq      = lane >> 4;

    // ---- GEMM1: K=128, NOUT=128, W1m ----
    f32x4 acc[4][4];
    #pragma unroll
    for (int mt = 0; mt < 4; ++mt)
        #pragma unroll
        for (int nt = 0; nt < 4; ++nt)
            #pragma unroll
            for (int q = 0; q < 4; ++q) acc[mt][nt][q] = 0.f;

    #pragma unroll
    for (int kc = 0; kc < 4; ++kc) {
        bf16x8 a[4];
        #pragma unroll
        for (int mt = 0; mt < 4; ++mt) {
            const int row = rowBase + mt * 16 + lrow;
            a[mt] = __builtin_bit_cast(bf16x8, A4[row * 16 + ((kc * 4 + kq) ^ (row & 7))]);
        }
        #pragma unroll
        for (int nt = 0; nt < 4; ++nt) {
            bf16x8 b = __builtin_bit_cast(bf16x8, pW1m[(size_t)((ctBase + nt) * 4 + kc) * 64 + lane]);
            #pragma unroll
            for (int mt = 0; mt < 4; ++mt)
                acc[mt][nt] = __builtin_amdgcn_mfma_f32_16x16x32_bf16(a[mt], b, acc[mt][nt], 0, 0, 0);
        }
    }
    __syncthreads();   // all waves done reading GEMM1 tile

    // ---- restage K=192 (stride 24): cols 0-63 = nfeats, 64-191 = h1 ----
    for (int idx = tid; idx < 128 * 8; idx += 256) {
        const int row = idx >> 3;
        const int u   = idx & 7;
        const int gr  = tileM + row;
        u32x4 o; o[0]=o[1]=o[2]=o[3]=0u;
        if (gr < NN) {
            const f32x4* pv = (const f32x4*)(nfeats + (size_t)gr * 64 + u * 8);
            f32x4 f0 = pv[0], f1 = pv[1];
            o[0] = pack2(f0[0], f0[1]); o[1] = pack2(f0[2], f0[3]);
            o[2] = pack2(f1[0], f1[1]); o[3] = pack2(f1[2], f1[3]);
        }
        A4[row * 24 + (u ^ (row & 7))] = o;
    }
    {
        float bb[4];
        #pragma unroll
        for (int nt = 0; nt < 4; ++nt) bb[nt] = b1m[(ctBase + nt) * 16 + lrow];
        #pragma unroll
        for (int mt = 0; mt < 4; ++mt) {
            #pragma unroll
            for (int j = 0; j < 4; ++j) {
                const int r  = rowBase + mt * 16 + kq * 4 + j;
                const int gr = tileM + r;
                const float msk = (gr < NN && inv[gr] > 0.f) ? 1.f : 0.f;
                #pragma unroll
                for (int nt = 0; nt < 4; ++nt) {
                    const int col = 64 + (ctBase + nt) * 16 + lrow;
                    const float val = acc[mt][nt][j] + bb[nt] * msk;
                    AS[(r * 24 + ((col >> 3) ^ (r & 7))) * 8 + (col & 7)] = (unsigned short)f2bf(val);
                }
            }
        }
    }
    __syncthreads();

    // ---- GEMM2: K=192, NOUT=128, W1a -> relu -> x1 ----
    f32x4 acc2[4][4];
    #pragma unroll
    for (int mt = 0; mt < 4; ++mt)
        #pragma unroll
        for (int nt = 0; nt < 4; ++nt)
            #pragma unroll
            for (int q = 0; q < 4; ++q) acc2[mt][nt][q] = 0.f;

    #pragma unroll
    for (int kc = 0; kc < 6; ++kc) {
        bf16x8 a[4];
        #pragma unroll
        for (int mt = 0; mt < 4; ++mt) {
            const int row = rowBase + mt * 16 + lrow;
            a[mt] = __builtin_bit_cast(bf16x8, A4[row * 24 + ((kc * 4 + kq) ^ (row & 7))]);
        }
        #pragma unroll
        for (int nt = 0; nt < 4; ++nt) {
            bf16x8 b = __builtin_bit_cast(bf16x8, pW1a[(size_t)((ctBase + nt) * 6 + kc) * 64 + lane]);
            #pragma unroll
            for (int mt = 0; mt < 4; ++mt)
                acc2[mt][nt] = __builtin_amdgcn_mfma_f32_16x16x32_bf16(a[mt], b, acc2[mt][nt], 0, 0, 0);
        }
    }
    {
        float bb[4];
        #pragma unroll
        for (int nt = 0; nt < 4; ++nt) bb[nt] = b1a[(ctBase + nt) * 16 + lrow];
        #pragma unroll
        for (int mt = 0; mt < 4; ++mt) {
            #pragma unroll
            for (int j = 0; j < 4; ++j) {
                const int gr = tileM + rowBase + mt * 16 + kq * 4 + j;
                if (gr < NN) {
                    #pragma unroll
                    for (int nt = 0; nt < 4; ++nt) {
                        const float v = fmaxf(acc2[mt][nt][j] + bb[nt], 0.f);
                        x1[(size_t)gr * 128 + (ctBase + nt) * 16 + lrow] = (unsigned short)f2bf(v);
                    }
                }
            }
        }
    }
}

// ================ fused layer-2 GEMM pair ================
// stage [xaggm2|eaggm] (K=192) -> GEMM W2m -> h2 regs
// restage [x1|h2] (K=192) -> GEMM W2a -> out = relu(...) f32
__global__ __launch_bounds__(256)
void k_gl2(const unsigned short* __restrict__ x1,
           const unsigned short* __restrict__ xaggm2, const unsigned short* __restrict__ eaggm,
           const float* __restrict__ inv,
           const float* __restrict__ b2m, const float* __restrict__ b2a,
           const u32x4* __restrict__ pW2m, const u32x4* __restrict__ pW2a,
           float* __restrict__ out)
{
    __shared__ __align__(16) u32x4 A4[128 * 24];   // 48 KB
    unsigned short* AS = (unsigned short*)A4;

    const int tid  = threadIdx.x;
    const int lane = tid & 63;
    const int w    = tid >> 6;
    const int tileM = blockIdx.x * 128;

    // ---- stage [xaggm2 (16u) | eaggm (8u)], K=192, stride 24 ----
    for (int idx = tid; idx < 128 * 16; idx += 256) {
        const int row = idx >> 4;
        const int u   = idx & 15;
        const int gr  = tileM + row;
        u32x4 o; o[0]=o[1]=o[2]=o[3]=0u;
        if (gr < NN) o = *(const u32x4*)(xaggm2 + (size_t)gr * 128 + u * 8);
        A4[row * 24 + (u ^ (row & 7))] = o;
    }
    for (int idx = tid; idx < 128 * 8; idx += 256) {
        const int row = idx >> 3;
        const int u   = 16 + (idx & 7);
        const int gr  = tileM + row;
        u32x4 o; o[0]=o[1]=o[2]=o[3]=0u;
        if (gr < NN) o = *(const u32x4*)(eaggm + (size_t)gr * 64 + (idx & 7) * 8);
        A4[row * 24 + (u ^ (row & 7))] = o;
    }
    __syncthreads();

    const int rowBase = (w >> 1) * 64;
    const int ctBase  = (w & 1) * 2;
    const int lrow    = lane & 15;
    const int kq      = lane >> 4;

    // ---- GEMM1: K=192, NOUT=64, W2m ----
    f32x4 acc[4][2];
    #pragma unroll
    for (int mt = 0; mt < 4; ++mt)
        #pragma unroll
        for (int nt = 0; nt < 2; ++nt)
            #pragma unroll
            for (int q = 0; q < 4; ++q) acc[mt][nt][q] = 0.f;

    #pragma unroll
    for (int kc = 0; kc < 6; ++kc) {
        bf16x8 a[4];
        #pragma unroll
        for (int mt = 0; mt < 4; ++mt) {
            const int row = rowBase + mt * 16 + lrow;
            a[mt] = __builtin_bit_cast(bf16x8, A4[row * 24 + ((kc * 4 + kq) ^ (row & 7))]);
        }
        #pragma unroll
        for (int nt = 0; nt < 2; ++nt) {
            bf16x8 b = __builtin_bit_cast(bf16x8, pW2m[(size_t)((ctBase + nt) * 6 + kc) * 64 + lane]);
            #pragma unroll
            for (int mt = 0; mt < 4; ++mt)
                acc[mt][nt] = __builtin_amdgcn_mfma_f32_16x16x32_bf16(a[mt], b, acc[mt][nt], 0, 0, 0);
        }
    }
    __syncthreads();

    // ---- restage: cols 0-127 = x1 rows (coalesced), cols 128-191 = h2 ----
    for (int idx = tid; idx < 128 * 16; idx += 256) {
        const int row = idx >> 4;
        const int u   = idx & 15;
        const int gr  = tileM + row;
        u32x4 o; o[0]=o[1]=o[2]=o[3]=0u;
        if (gr < NN) o = *(const u32x4*)(x1 + (size_t)gr * 128 + u * 8);
        A4[row * 24 + (u ^ (row & 7))] = o;
    }
    {
        float bb[2];
        #pragma unroll
        for (int nt = 0; nt < 2; ++nt) bb[nt] = b2m[(ctBase + nt) * 16 + lrow];
        #pragma unroll
        for (int mt = 0; mt < 4; ++mt) {
            #pragma unroll
            for (int j = 0; j < 4; ++j) {
                const int r  = rowBase + mt * 16 + kq * 4 + j;
                const int gr = tileM + r;
                const float msk = (gr < NN && inv[gr] > 0.f) ? 1.f : 0.f;
                #pragma unroll
                for (int nt = 0; nt < 2; ++nt) {
                    const int col = 128 + (ctBase + nt) * 16 + lrow;
                    const float val = acc[mt][nt][j] + bb[nt] * msk;
                    AS[(r * 24 + ((col >> 3) ^ (r & 7))) * 8 + (col & 7)] = (unsigned short)f2bf(val);
                }
            }
        }
    }
    __syncthreads();

    // ---- GEMM2: K=192, NOUT=64, W2a -> relu -> out f32 ----
    f32x4 acc2[4][2];
    #pragma unroll
    for (int mt = 0; mt < 4; ++mt)
        #pragma unroll
        for (int nt = 0; nt < 2; ++nt)
            #pragma unroll
            for (int q = 0; q < 4; ++q) acc2[mt][nt][q] = 0.f;

    #pragma unroll
    for (int kc = 0; kc < 6; ++kc) {
        bf16x8 a[4];
        #pragma unroll
        for (int mt = 0; mt < 4; ++mt) {
            const int row = rowBase + mt * 16 + lrow;
            a[mt] = __builtin_bit_cast(bf16x8, A4[row * 24 + ((kc * 4 + kq) ^ (row & 7))]);
        }
        #pragma unroll
        for (int nt = 0; nt < 2; ++nt) {
            bf16x8 b = __builtin_bit_cast(bf16x8, pW2a[(size_t)((ctBase + nt) * 6 + kc) * 64 + lane]);
            #pragma unroll
            for (int mt = 0; mt < 4; ++mt)
                acc2[mt][nt] = __builtin_amdgcn_mfma_f32_16x16x32_bf16(a[mt], b, acc2[mt][nt], 0, 0, 0);
        }
    }
    {
        float bb[2];
        #pragma unroll
        for (int nt = 0; nt < 2; ++nt) bb[nt] = b2a[(ctBase + nt) * 16 + lrow];
        #pragma unroll
        for (int mt = 0; mt < 4; ++mt) {
            #pragma unroll
            for (int j = 0; j < 4; ++j) {
                const int gr = tileM + rowBase + mt * 16 + kq * 4 + j;
                if (gr < NN) {
                    #pragma unroll
                    for (int nt = 0; nt < 2; ++nt) {
                        const float v = fmaxf(acc2[mt][nt][j] + bb[nt], 0.f);
                        out[(size_t)gr * 64 + (ctBase + nt) * 16 + lrow] = v;
                    }
                }
            }
        }
    }
}

extern "C" void kernel_launch(void* const* d_in, const int* in_sizes, int n_in,
                              void* d_out, int out_size, void* d_ws, size_t ws_size,
                              hipStream_t stream) {
    const float* nfeats = (const float*)d_in[0];
    const float* efeats = (const float*)d_in[1];
    const int*   src    = (const int*)d_in[2];
    const int*   dst    = (const int*)d_in[3];
    const float* W1m = (const float*)d_in[4];
    const float* b1m = (const float*)d_in[5];
    const float* W1a = (const float*)d_in[6];
    const float* b1a = (const float*)d_in[7];
    const float* W2m = (const float*)d_in[8];
    const float* b2m = (const float*)d_in[9];
    const float* W2a = (const float*)d_in[10];
    const float* b2a = (const float*)d_in[11];
    float* out = (float*)d_out;

    char* ws = (char*)d_ws;
    unsigned short* eaggm  = (unsigned short*)(ws + 0);          // N*64 bf16  = 12.8 MB
    unsigned short* xaggm1 = (unsigned short*)(ws + 12800000);   // N*64 bf16  = 12.8 MB
    unsigned short* xaggm2 = (unsigned short*)(ws + 25600000);   // N*128 bf16 = 25.6 MB
    unsigned short* x1     = (unsigned short*)(ws + 51200000);   // N*128 bf16 = 25.6 MB
    int2*           ep2    = (int2*)(ws + 76800000);             // E int2 = 12.8 MB
    int*            cnt    = (int*)(ws + 89600000);              // N int
    int*            offs   = (int*)(ws + 90000000);              // N int
    int*            offg   = (int*)(ws + 90400000);              // N int
    int*            cur    = (int*)(ws + 90800000);              // N int
    int*            part   = (int*)(ws + 91200000);              // 512 int
    float*          inv    = (float*)(ws + 91202048);            // N f32
    u32x4* pW1m = (u32x4*)(ws + 91602048);                       // 32 KB
    u32x4* pW1a = (u32x4*)(ws + 91634816);                       // 48 KB
    u32x4* pW2m = (u32x4*)(ws + 91683968);                       // 24 KB
    u32x4* pW2a = (u32x4*)(ws + 91708544);                       // 24 KB

    // init: zero cnt (kernel, NOT hipMemsetAsync — in-graph fill measured 240 µs in R3)
    // + pack all 4 weights. One launch.
    k_init<<<423, 256, 0, stream>>>(cnt, W1m, pW1m, W1a, pW1a, W2m, pW2m, W2a, pW2a);

    // CSR bucketing by dst
    k_count  <<<(EE + 255) / 256, 256, 0, stream>>>(dst, cnt);
    k_scan1  <<<NB_SCAN, 256, 0, stream>>>(cnt, offs, part);
    k_scan2  <<<1, 512, 0, stream>>>(part);
    k_scan3  <<<NB_SCAN, 256, 0, stream>>>(cnt, offs, part, offg, cur, inv);
    k_scatter<<<(EE + 255) / 256, 256, 0, stream>>>(dst, src, cur, ep2);

    const int NBAGG = NN / 4;          // 25000 blocks, 1 wave per node (max TLP for gathers)
    const int NBG   = (NN + 127) / 128; // 782

    // gather-means (dedicated kernels — R5 showed fusing these into GEMM grids is latency-bound)
    k_agg01<<<NBAGG, 256, 0, stream>>>(efeats, nfeats, ep2, offg, cnt, inv, eaggm, xaggm1);
    // fused layer-1 GEMM pair: [xaggm1|eaggm]@W1m -> h1 -> [nfeats|h1]@W1a -> x1
    k_gl1<<<NBG, 256, 0, stream>>>(nfeats, xaggm1, eaggm, inv, b1m, b1a, pW1m, pW1a, x1);
    // layer-2 gather-mean
    k_agg2<<<NBAGG, 256, 0, stream>>>(x1, ep2, offg, cnt, inv, xaggm2);
    // fused layer-2 GEMM pair: [xaggm2|eaggm]@W2m -> h2 -> [x1|h2]@W2a -> out
    k_gl2<<<NBG, 256, 0, stream>>>(x1, xaggm2, eaggm, inv, b2m, b2a, pW2m, pW2a, out);
}